// Round 10
// baseline (212.103 us; speedup 1.0000x reference)
//
#include <hip/hip_runtime.h>

// Chamfer loss between subsampled point clouds — 1 kernel + 40B memset.
// srcA: (64000,2) fp32 -> A = 8000 pts  (fp32 linspace trunc, matches jnp)
// srcB: (80000,2) fp32 -> B = 10000 pts
// out  = 0.5 * ( mean_i min_j |A_i - B_j| + mean_j min_i |A_i - B_j| )
//
// Session ledger (measured):
//  - per-element device atomics: 81us storm (round 6). Coarse atomics
//    (~530 total here) are negligible.
//  - cooperative grid.sync over 511 blocks: ~64us cross-XCD drain (round 8).
//  - inter-dispatch gap ~8us; window = 41us harness fill + our work + gaps.
//    Rounds 1/7/9 all ~75-78us => dispatch count is the remaining lever.
//  - chamfer structure (LDS float4 broadcast cols, expanded 3-op inner,
//    RPT=8, 511 blocks): ~9us, proven rounds 7-9. Group-reduce pattern
//    proven round 4/7 (~4.5us over 282 blocks).
//
// This version: fuse the reduce into the chamfer kernel via a per-row-group
// ticket (9 groups x 51/64 blocks). Last block of each group reduces that
// group's rows (overlaps other groups' compute); a 2nd-level ticket makes
// the 9th reducer sum 9 slots in fixed order and plain-store *out.
// Only init needed: 10 counters -> hipMemsetAsync(40 B) (graph-capturable;
// the harness's own reset() enqueues hipMemsetAsync).
//
// Expanded form: argmin_j |p-q_j|^2 == argmax_j (2p.q_j - |q_j|^2);
//   M = fmax(M, fma(px,qx, fma(py,qy, -|q|^2)))  = 3 VALU ops/pair.
// |p|^2 re-added at store; clamp-at-0 + sqrt in the reduce (monotone).

#define SRC_A 64000
#define SRC_B 80000
#define NA 8000
#define NB 10000

#define BLOCK 256
#define RPT 8
#define RPB (BLOCK * RPT)      // 2048 rows per block
#define SLICE 157              // cols per block (staged once in LDS)

#define G1 4                   // ceil(NA/RPB)   row-groups, pass 1 (A rows)
#define S1 64                  // ceil(NB/SLICE) col-slices, pass 1 (B cols)
#define G2 5                   // ceil(NB/RPB)   row-groups, pass 2 (B rows)
#define S2 51                  // ceil(NA/SLICE) col-slices, pass 2 (A cols)
#define NBLK1 (G1 * S1)        // 256
#define NBLK2 (G2 * S2)        // 255  -> 511 blocks (~2/CU, balanced)
#define NGRP (G1 + G2)         // 9 row-groups total

#define PSTR1 (G1 * RPB)       // 8192  (padded rows, pass 1)
#define PSTR2 (G2 * RPB)       // 10240 (padded rows, pass 2)
#define PART2_OFF (S1 * PSTR1)             // floats: P1 @ 0, P2 @ here
#define CNT_OFF (PART2_OFF + S2 * PSTR2)   // floats: 10 uint counters
#define SLOT_OFF (CNT_OFF + 16)            // floats: 9 group partial sums
#define CNT_BYTES 40                       // 9 group counters + 1 final
#define CNT_BYTE_OFF (CNT_OFF * 4)

#define DELTA_A ((float)(SRC_A - 1) / (float)(NA - 1))
#define DELTA_B ((float)(SRC_B - 1) / (float)(NB - 1))

__global__ __launch_bounds__(BLOCK) void chamfer_one(
        const float2* __restrict__ srcA, const float2* __restrict__ srcB,
        float* __restrict__ ws, float* __restrict__ out) {
    const bool p1 = (int)blockIdx.x < NBLK1;
    const float2* rowsS; const float2* colsS; float* P;
    float rowD, colD, scale;
    int rowMax, colMax, nrows, ncols, g, s, pstr, Sgrp;
    if (p1) {
        int f = (int)blockIdx.x;
        g = f % G1; s = f / G1;
        rowsS = srcA; rowD = DELTA_A; rowMax = SRC_A - 1; nrows = NA;
        colsS = srcB; colD = DELTA_B; colMax = SRC_B - 1; ncols = NB;
        P = ws; pstr = PSTR1; Sgrp = S1; scale = 0.5f / (float)NA;
    } else {
        int f = (int)blockIdx.x - NBLK1;
        g = f % G2; s = f / G2;
        rowsS = srcB; rowD = DELTA_B; rowMax = SRC_B - 1; nrows = NB;
        colsS = srcA; colD = DELTA_A; colMax = SRC_A - 1; ncols = NA;
        P = ws + PART2_OFF; pstr = PSTR2; Sgrp = S2; scale = 0.5f / (float)NB;
    }

    // ---- phase 1: stage column slice in LDS as (2qx, 2qy, -|q|^2, 0) ----
    __shared__ __align__(16) float4 sc[SLICE];
    int c0 = s * SLICE;
    int cw = ncols - c0; if (cw > SLICE) cw = SLICE;
    if ((int)threadIdx.x < cw) {
        int cidx = (int)((float)(c0 + (int)threadIdx.x) * colD);
        if (cidx > colMax) cidx = colMax;
        float2 q = colsS[cidx];
        float n2 = fmaf(q.x, q.x, q.y * q.y);
        sc[threadIdx.x] = make_float4(q.x + q.x, q.y + q.y, -n2, 0.0f);
    }
    __syncthreads();

    // rows: inline linspace gather (clamp load, guard store)
    float px[RPT], py[RPT], pp[RPT], M[RPT];
    int r0 = g * RPB + (int)threadIdx.x;
#pragma unroll
    for (int i = 0; i < RPT; ++i) {
        int r = r0 + i * BLOCK;
        int l = r < nrows ? r : nrows - 1;
        int ridx = (int)((float)l * rowD);
        if (ridx > rowMax) ridx = rowMax;
        float2 q = rowsS[ridx];
        px[i] = q.x; py[i] = q.y;
        pp[i] = fmaf(q.x, q.x, q.y * q.y);
        M[i] = -__builtin_inff();
    }

    if (cw == SLICE) {
        // hot path (113 of 115 slices): compile-time trip count
#pragma unroll 4
        for (int k = 0; k < SLICE; ++k) {
            float4 q = sc[k];  // broadcast across the wave: conflict-free
#pragma unroll
            for (int i = 0; i < RPT; ++i)
                M[i] = fmaxf(M[i], fmaf(px[i], q.x, fmaf(py[i], q.y, q.z)));
        }
    } else {
        for (int k = 0; k < cw; ++k) {
            float4 q = sc[k];
#pragma unroll
            for (int i = 0; i < RPT; ++i)
                M[i] = fmaxf(M[i], fmaf(px[i], q.x, fmaf(py[i], q.y, q.z)));
        }
    }

    // plain coalesced stores of partial min d^2 (no atomics)
#pragma unroll
    for (int i = 0; i < RPT; ++i) {
        int r = r0 + i * BLOCK;
        if (r < nrows) P[s * pstr + r] = pp[i] - M[i];
    }

    // ---- group ticket: last slice-block of this row-group reduces it ----
    unsigned* cnt = reinterpret_cast<unsigned*>(ws + CNT_OFF);
    float* slot = ws + SLOT_OFF;
    int gid = p1 ? g : (G1 + g);

    __threadfence();   // release partial stores agent-wide (cross-XCD)
    __shared__ unsigned tick;
    if (threadIdx.x == 0)
        tick = __hip_atomic_fetch_add(cnt + gid, 1u, __ATOMIC_ACQ_REL,
                                      __HIP_MEMORY_SCOPE_AGENT);
    __syncthreads();
    if ((int)tick != Sgrp - 1) return;   // not last: done (no spin anywhere)

    // ---- phase 2: reduce this row-group (acquire via the ACQ_REL ticket) ----
    float sum = 0.0f;
#pragma unroll
    for (int i = 0; i < RPT; ++i) {
        int r = g * RPB + i * BLOCK + (int)threadIdx.x;
        if (r < nrows) {
            float mn = __builtin_inff();
#pragma unroll 8
            for (int c = 0; c < Sgrp; ++c)
                mn = fminf(mn, P[c * pstr + r]);
            sum += sqrtf(fmaxf(mn, 0.0f));  // expanded form can round < 0
        }
    }
    sum *= scale;
    for (int off = 32; off > 0; off >>= 1) sum += __shfl_down(sum, off, 64);
    __shared__ float red[4];
    if ((threadIdx.x & 63) == 0) red[threadIdx.x >> 6] = sum;
    __syncthreads();

    if (threadIdx.x == 0) {
        slot[gid] = red[0] + red[1] + red[2] + red[3];
        __threadfence();   // release slot store
        unsigned f = __hip_atomic_fetch_add(cnt + NGRP, 1u, __ATOMIC_ACQ_REL,
                                            __HIP_MEMORY_SCOPE_AGENT);
        if (f == NGRP - 1) {   // 9th reducer: fixed-order deterministic sum
            float t = 0.0f;
#pragma unroll
            for (int i = 0; i < NGRP; ++i) t += slot[i];
            *out = t;          // single plain store; no out pre-init needed
        }
    }
}

extern "C" void kernel_launch(void* const* d_in, const int* in_sizes, int n_in,
                              void* d_out, int out_size, void* d_ws, size_t ws_size,
                              hipStream_t stream) {
    (void)in_sizes; (void)n_in; (void)out_size; (void)ws_size;
    const float2* srcA = (const float2*)d_in[0];  // img_render_points (1000*64*2)
    const float2* srcB = (const float2*)d_in[1];  // ref point cloud (80000*2)
    float* ws = (float*)d_ws;
    float* out = (float*)d_out;

    // zero the 10 ticket counters (ws is re-poisoned every iteration);
    // hipMemsetAsync is graph-capturable (harness reset() uses it itself).
    hipMemsetAsync((char*)d_ws + CNT_BYTE_OFF, 0, CNT_BYTES, stream);
    chamfer_one<<<NBLK1 + NBLK2, BLOCK, 0, stream>>>(srcA, srcB, ws, out);
}

// Round 11
// 77.260 us; speedup vs baseline: 2.7453x; 2.7453x over previous
//
#include <hip/hip_runtime.h>

// Chamfer loss between subsampled point clouds — 2 dispatches, no exotic sync.
// srcA: (64000,2) fp32 -> A = 8000 pts  (fp32 linspace trunc, matches jnp)
// srcB: (80000,2) fp32 -> B = 10000 pts
// out  = 0.5 * ( mean_i min_j |A_i - B_j| + mean_j min_i |A_i - B_j| )
//
// FINAL structure. Session ledger (all measured on MI355X):
//  - per-element device atomics: +70us (round 6, 81us total).
//  - cooperative grid.sync over 511 blocks: +64us cross-XCD drain (round 8).
//  - per-block __threadfence + ticket finalize: +160us — agent-scope release
//    = L2 writeback per block across 8 non-coherent XCDs (round 10, 175us).
//  - stream-ordered dispatch boundary: ~8us. THE KERNEL BOUNDARY IS THE
//    CHEAPEST CROSS-XCD BARRIER ON CDNA4. Two dispatches is optimal here.
//  - chamfer structure below (LDS float4 broadcast cols, expanded 3-op
//    inner, RPT=8, 511 balanced blocks): ~9us vs 6.1us VALU floor.
//  - 282-block slice-parallel reduce: ~4.5us.
//  - window = ~41us harness 256MiB poison-fill (80-84% HBM peak, ±4us
//    run-to-run) + ~12us harness residual + our ~21.5us => ~75us is the
//    structural floor within measurement noise.
//
// Expanded form: argmin_j |p-q_j|^2 == argmax_j (2p.q_j - |q_j|^2);
//   M = fmax(M, fma(px,qx, fma(py,qy, -|q|^2)))  = 3 VALU ops/pair.
// |p|^2 re-added at store; clamp-at-0 + sqrt in the reduce (monotone).

#define SRC_A 64000
#define SRC_B 80000
#define NA 8000
#define NB 10000

#define BLOCK 256
#define RPT 8
#define RPB (BLOCK * RPT)      // 2048 rows per block
#define SLICE 157              // cols per block (staged once in LDS)

#define G1 4                   // ceil(NA/RPB)   row-groups, pass 1 (A rows)
#define S1 64                  // ceil(NB/SLICE) col-slices, pass 1 (B cols)
#define G2 5                   // ceil(NB/RPB)   row-groups, pass 2 (B rows)
#define S2 51                  // ceil(NA/SLICE) col-slices, pass 2 (A cols)
#define NBLK1 (G1 * S1)        // 256
#define NBLK2 (G2 * S2)        // 255  -> 511 blocks (~2/CU, balanced)

#define PSTR1 (G1 * RPB)       // 8192  (padded rows, pass 1)
#define PSTR2 (G2 * RPB)       // 10240 (padded rows, pass 2)
#define PART2_OFF (S1 * PSTR1) // floats; P1 @ 0, P2 @ PART2_OFF (~4.2 MB total)

#define DELTA_A ((float)(SRC_A - 1) / (float)(NA - 1))
#define DELTA_B ((float)(SRC_B - 1) / (float)(NB - 1))

__global__ __launch_bounds__(BLOCK) void chamfer_partial(
        const float2* __restrict__ srcA, const float2* __restrict__ srcB,
        float* __restrict__ ws, float* __restrict__ out) {
    if (blockIdx.x == 0 && threadIdx.x == 0) *out = 0.0f;  // init for reduce's atomicAdd

    const bool p1 = (int)blockIdx.x < NBLK1;
    const float2* rowsS; const float2* colsS; float* P;
    float rowD, colD; int rowMax, colMax, nrows, ncols, g, s, pstr;
    if (p1) {
        int f = (int)blockIdx.x;
        g = f % G1; s = f / G1;
        rowsS = srcA; rowD = DELTA_A; rowMax = SRC_A - 1; nrows = NA;
        colsS = srcB; colD = DELTA_B; colMax = SRC_B - 1; ncols = NB;
        P = ws; pstr = PSTR1;
    } else {
        int f = (int)blockIdx.x - NBLK1;
        g = f % G2; s = f / G2;
        rowsS = srcB; rowD = DELTA_B; rowMax = SRC_B - 1; nrows = NB;
        colsS = srcA; colD = DELTA_A; colMax = SRC_A - 1; ncols = NA;
        P = ws + PART2_OFF; pstr = PSTR2;
    }

    // stage this block's column slice in LDS as (2qx, 2qy, -|q|^2, 0)
    __shared__ __align__(16) float4 sc[SLICE];
    int c0 = s * SLICE;
    int cw = ncols - c0; if (cw > SLICE) cw = SLICE;
    if ((int)threadIdx.x < cw) {
        int cidx = (int)((float)(c0 + (int)threadIdx.x) * colD);
        if (cidx > colMax) cidx = colMax;
        float2 q = colsS[cidx];
        float n2 = fmaf(q.x, q.x, q.y * q.y);
        sc[threadIdx.x] = make_float4(q.x + q.x, q.y + q.y, -n2, 0.0f);
    }
    __syncthreads();

    // rows: inline linspace gather (clamp load, guard store)
    float px[RPT], py[RPT], pp[RPT], M[RPT];
    int r0 = g * RPB + (int)threadIdx.x;
#pragma unroll
    for (int i = 0; i < RPT; ++i) {
        int r = r0 + i * BLOCK;
        int l = r < nrows ? r : nrows - 1;
        int ridx = (int)((float)l * rowD);
        if (ridx > rowMax) ridx = rowMax;
        float2 q = rowsS[ridx];
        px[i] = q.x; py[i] = q.y;
        pp[i] = fmaf(q.x, q.x, q.y * q.y);
        M[i] = -__builtin_inff();
    }

    if (cw == SLICE) {
        // hot path (113 of 115 slices): compile-time trip count
#pragma unroll 4
        for (int k = 0; k < SLICE; ++k) {
            float4 q = sc[k];  // broadcast across the wave: conflict-free
#pragma unroll
            for (int i = 0; i < RPT; ++i)
                M[i] = fmaxf(M[i], fmaf(px[i], q.x, fmaf(py[i], q.y, q.z)));
        }
    } else {
        for (int k = 0; k < cw; ++k) {
            float4 q = sc[k];
#pragma unroll
            for (int i = 0; i < RPT; ++i)
                M[i] = fmaxf(M[i], fmaf(px[i], q.x, fmaf(py[i], q.y, q.z)));
        }
    }

    // plain coalesced stores of partial min d^2 (no atomics)
#pragma unroll
    for (int i = 0; i < RPT; ++i) {
        int r = r0 + i * BLOCK;
        if (r < nrows) P[s * pstr + r] = pp[i] - M[i];
    }
}

// ---- reduce: 64 rows/block x 4 chunk-slices, coalesced, then LDS+shuffle ----
#define RB_ROWS 64
#define RB1 125   // 8000/64 (exact)
#define RB2 157   // ceil(10000/64)

__global__ __launch_bounds__(BLOCK) void reduce_out(const float* __restrict__ ws,
                                                    float* __restrict__ out) {
    int t  = (int)threadIdx.x;
    int rl = t & 63;        // row within block
    int sl = t >> 6;        // chunk-slice 0..3
    const bool p1 = (int)blockIdx.x < RB1;
    const float* P; int nrows, nch, pstr, rbase; float scale;
    if (p1) {
        P = ws;             nrows = NA; nch = S1; pstr = PSTR1;
        rbase = (int)blockIdx.x * RB_ROWS;         scale = 0.5f / (float)NA;
    } else {
        P = ws + PART2_OFF; nrows = NB; nch = S2; pstr = PSTR2;
        rbase = ((int)blockIdx.x - RB1) * RB_ROWS; scale = 0.5f / (float)NB;
    }
    int r = rbase + rl;                 // < pstr (padded); value guarded at use
    int per = (nch + 3) >> 2;
    int cb = sl * per;
    int ce = cb + per; if (ce > nch) ce = nch;

    float mn = __builtin_inff();
#pragma unroll 8
    for (int c = cb; c < ce; ++c) mn = fminf(mn, P[c * pstr + r]);

    __shared__ float red[4][RB_ROWS];
    red[sl][rl] = mn;
    __syncthreads();

    if (t < 64) {
        float m = fminf(fminf(red[0][rl], red[1][rl]),
                        fminf(red[2][rl], red[3][rl]));
        m = fmaxf(m, 0.0f);  // expanded form can round slightly negative
        float v = (r < nrows) ? sqrtf(m) * scale : 0.0f;
        for (int off = 32; off > 0; off >>= 1) v += __shfl_down(v, off, 64);
        if (rl == 0) atomicAdd(out, v);
    }
}

extern "C" void kernel_launch(void* const* d_in, const int* in_sizes, int n_in,
                              void* d_out, int out_size, void* d_ws, size_t ws_size,
                              hipStream_t stream) {
    (void)in_sizes; (void)n_in; (void)out_size; (void)ws_size;
    const float2* srcA = (const float2*)d_in[0];  // img_render_points (1000*64*2)
    const float2* srcB = (const float2*)d_in[1];  // ref point cloud (80000*2)
    float* ws = (float*)d_ws;
    float* out = (float*)d_out;

    chamfer_partial<<<NBLK1 + NBLK2, BLOCK, 0, stream>>>(srcA, srcB, ws, out);
    reduce_out<<<RB1 + RB2, BLOCK, 0, stream>>>(ws, out);
}